// Round 22
// baseline (47.493 us; speedup 1.0000x reference)
//
#include <hip/hip_runtime.h>
#include <math.h>

// Problem constants
constexpr int BN  = 16;    // batch
constexpr int HH  = 224;
constexpr int WW  = 224;
constexpr int CI  = 8;     // input channels
constexpr int FF  = 256;   // filter feature dim
constexpr int NC  = 16;    // output channels
constexpr int NP  = 1152;  // CI*NC*3*3 dynamic params per sample
// reference patch index p = cin*9 + dy*3 + dx ; w[b][p][c] = dyn[b][p*16+c]
// MFMA K-ordering: k = tap*8 + cin, tap = dy*3+dx (taps 9..11 pad=0)
//
// Budget (r18 reps + r20 replay): k_h 1.7 + k_dyn ~3 + k_conv 14.3 ~= 19 us
// of kernel time; the rest of the ~39-46 us total is dispatch envelope (and a
// +-6 us bimodal harness mode). This round cuts 3 dispatches -> 2: k_h+k_dyn
// fused into 144 independent blocks (9 col-groups x 16 samples), each
// recomputing its sample's h in-block (cheap, parallel, 9x redundant) and
// writing FINAL dyn columns with bd folded. Deterministic: no atomics, no
// cross-kernel init, every output element written by exactly one thread.
// k_conv: exact r17 body (measured ~14.3 us ~ 1.15x memory floor).

typedef __attribute__((ext_vector_type(8))) short short8;   // 8 bf16 = 4 VGPR
typedef __attribute__((ext_vector_type(4))) float f32x4;

__device__ __forceinline__ float elu_f(float x) {
    return x > 0.0f ? x : (__expf(x) - 1.0f);
}

// split f32 -> bf16 hi (truncate) + bf16 lo (residual, truncate): v ~= hi+lo
__device__ __forceinline__ void split8(const float* v, short8& hi, short8& lo) {
#pragma unroll
    for (int j = 0; j < 8; ++j) {
        const unsigned u = __float_as_uint(v[j]);
        hi[j] = (short)(u >> 16);
        const float hf = __uint_as_float(u & 0xffff0000u);
        lo[j] = (short)(__float_as_uint(v[j] - hf) >> 16);
    }
}

// ------ fused kernel 1+2: per-block h (full 256) -> final dyn columns -------
// grid (9, 16) = 144 blocks, 128 threads. Phase A: h = elu(fi@W1+b1), cols t
// and t+128, two k-chains each (coalesced W1 reads across lanes; W1 slice is
// L2-hot after the first blocks). Phase B: thread t writes FINAL dyn column
// cg*128+t for sample b (bd folded). cg==0 blocks also produce the bias.
__global__ __launch_bounds__(128) void k_hdyn(const float* __restrict__ fi,
                                              const float* __restrict__ W1,
                                              const float* __restrict__ b1,
                                              const float* __restrict__ Wd,
                                              const float* __restrict__ bd,
                                              const float* __restrict__ Wb,
                                              const float* __restrict__ bb,
                                              const float* __restrict__ dfn,
                                              float* __restrict__ w_all,
                                              float* __restrict__ bias_all) {
    __shared__ float fis[FF];
    __shared__ float hs[FF];
    const int cg = blockIdx.x;               // 0..8 (column group)
    const int b  = blockIdx.y;               // 0..15 (sample)
    const int t  = threadIdx.x;              // 0..127

    fis[t]       = fi[b * FF + t];
    fis[t + 128] = fi[b * FF + t + 128];
    __syncthreads();

    // ---- phase A: h columns t and t+128 (2 independent k-chains each) ----
    {
        float a0 = b1[t],       a1 = 0.0f;   // col t
        float c0 = b1[t + 128], c1 = 0.0f;   // col t+128
#pragma unroll 8
        for (int k = 0; k < 128; ++k) {
            a0 = fmaf(fis[k],       W1[k * FF + t],               a0);
            c0 = fmaf(fis[k],       W1[k * FF + t + 128],         c0);
            a1 = fmaf(fis[k + 128], W1[(k + 128) * FF + t],       a1);
            c1 = fmaf(fis[k + 128], W1[(k + 128) * FF + t + 128], c1);
        }
        hs[t]       = elu_f(a0 + a1);
        hs[t + 128] = elu_f(c0 + c1);
    }
    __syncthreads();

    // ---- phase B: final dyn column i (bd folded), 2 k-chains ----
    const int i = cg * 128 + t;              // output column < 1152
    float a0 = bd[i], a1 = 0.0f;
#pragma unroll 8
    for (int k = 0; k < 128; ++k) {
        a0 = fmaf(hs[k],       Wd[(size_t)k * NP + i],         a0);
        a1 = fmaf(hs[k + 128], Wd[(size_t)(k + 128) * NP + i], a1);
    }
    w_all[b * NP + i] = a0 + a1;

    if (cg == 0 && t < NC) {                 // bias rides along here
        float s0 = bb[t] + dfn[t], s1 = 0.0f;
#pragma unroll 8
        for (int k = 0; k < 128; ++k) {
            s0 = fmaf(hs[k],       Wb[k * NC + t],         s0);
            s1 = fmaf(hs[k + 128], Wb[(k + 128) * NC + t], s1);
        }
        bias_all[b * NC + t] = s0 + s1;
    }
}

// ---------------- kernel 3: dynamic conv as per-sample MFMA GEMM -------------
// [r17 body verbatim, measured ~14.3 us ~ 1.15x memory floor]
__global__ __launch_bounds__(128) void k_conv(const float* __restrict__ in,
                                              const float* __restrict__ w_all,
                                              const float* __restrict__ bias_all,
                                              float* __restrict__ out) {
    __shared__ short8 lsA[4][116][2];        // [row][px][hi/lo] = 14,848 B

    const int b    = blockIdx.z;
    const int half = blockIdx.x;             // 0/1: x-half of the rows
    const int t    = threadIdx.x;
    const int wid  = t >> 6;
    const int lane = t & 63;
    const int cl   = lane & 15;
    const int g    = lane >> 4;              // k-group 0..3
    const int yb0  = blockIdx.y * 2;
    const int xb0  = half * 112;

    // ---- stage 4 rows x 114 px (hi/lo pre-split, zero-filled halo) ----
    for (int s = t; s < 456; s += 128) {
        const int r  = s / 114;
        const int j  = s - r * 114;
        const int gy = yb0 - 1 + r;
        const int gx = xb0 - 1 + j;
        const bool ok = ((unsigned)gy < (unsigned)HH) &&
                        ((unsigned)gx < (unsigned)WW);
        float av[8] = {0.f, 0.f, 0.f, 0.f, 0.f, 0.f, 0.f, 0.f};
        if (ok) {
            const float4* pp =
                (const float4*)(in + ((size_t)(b * HH + gy) * WW + gx) * CI);
            const float4 a0 = pp[0];
            const float4 a1 = pp[1];
            av[0] = a0.x; av[1] = a0.y; av[2] = a0.z; av[3] = a0.w;
            av[4] = a1.x; av[5] = a1.y; av[6] = a1.z; av[7] = a1.w;
        }
        short8 hi, lo;
        split8(av, hi, lo);
        lsA[r][j][0] = hi;
        lsA[r][j][1] = lo;
    }

    // ---- per-lane tap geometry for the 3 k-chunks ----
    int  dyL[3], dxL[3];
    bool real[3];
#pragma unroll
    for (int c = 0; c < 3; ++c) {
        const int tap = c * 4 + g;
        real[c] = (tap < 9);
        const int tp = real[c] ? tap : 0;
        dyL[c] = tp / 3;
        dxL[c] = tp - 3 * dyL[c];
    }

    // ---- weight fragments (hi/lo), loaded once per wave ----
    const float* __restrict__ wq = w_all + b * NP;
    short8 bhi0, blo0, bhi1, blo1, bhi2, blo2;
    {
        float wv[8];
#pragma unroll
        for (int i = 0; i < 8; ++i)
            wv[i] = real[0] ? wq[(i * 9 + (0 * 4 + g)) * NC + cl] : 0.0f;
        split8(wv, bhi0, blo0);
#pragma unroll
        for (int i = 0; i < 8; ++i)
            wv[i] = real[1] ? wq[(i * 9 + (1 * 4 + g)) * NC + cl] : 0.0f;
        split8(wv, bhi1, blo1);
#pragma unroll
        for (int i = 0; i < 8; ++i)
            wv[i] = real[2] ? wq[(i * 9 + (2 * 4 + g)) * NC + cl] : 0.0f;
        split8(wv, bhi2, blo2);
    }

    __syncthreads();

    const float4 bias4 = ((const float4*)(bias_all + b * NC))[g];
    const int y = yb0 + wid;
    const size_t orow = ((size_t)(b * HH + y) * WW) * NC;

#pragma unroll 1
    for (int tx = 0; tx < 7; ++tx) {
        const int x0 = xb0 + tx * 16;
        f32x4 accM = {bias4.x, bias4.y, bias4.z, bias4.w};   // hi*hi
        f32x4 accL = {0.f, 0.f, 0.f, 0.f};                   // hiW*loA
        f32x4 accH = {0.f, 0.f, 0.f, 0.f};                   // loW*hiA

#pragma unroll
        for (int c = 0; c < 3; ++c) {
            const int j = tx * 16 + cl + dxL[c];             // 0..113
            const int r = wid + dyL[c];                      // 0..3
            const short8 ahi = lsA[r][j][0];
            const short8 alo = lsA[r][j][1];
            const short8 bh = (c == 0) ? bhi0 : (c == 1) ? bhi1 : bhi2;
            const short8 bl = (c == 0) ? blo0 : (c == 1) ? blo1 : blo2;
            accM = __builtin_amdgcn_mfma_f32_16x16x32_bf16(bh, ahi, accM, 0, 0, 0);
            accL = __builtin_amdgcn_mfma_f32_16x16x32_bf16(bh, alo, accL, 0, 0, 0);
            accH = __builtin_amdgcn_mfma_f32_16x16x32_bf16(bl, ahi, accH, 0, 0, 0);
        }

        // ---- epilogue: elu + ONE float4 store (4 channels of pixel x0+cl) --
        float4 res;
        res.x = elu_f(accM[0] + accL[0] + accH[0]);
        res.y = elu_f(accM[1] + accL[1] + accH[1]);
        res.z = elu_f(accM[2] + accL[2] + accH[2]);
        res.w = elu_f(accM[3] + accL[3] + accH[3]);
        ((float4*)(out + orow + (size_t)(x0 + cl) * NC))[g] = res;
    }
}

extern "C" void kernel_launch(void* const* d_in, const int* in_sizes, int n_in,
                              void* d_out, int out_size, void* d_ws, size_t ws_size,
                              hipStream_t stream) {
    const float* inpt = (const float*)d_in[0];
    const float* fi   = (const float*)d_in[1];
    const float* W1   = (const float*)d_in[2];
    const float* b1   = (const float*)d_in[3];
    const float* Wd   = (const float*)d_in[4];
    const float* bd   = (const float*)d_in[5];
    const float* Wb   = (const float*)d_in[6];
    const float* bb   = (const float*)d_in[7];
    const float* dfn  = (const float*)d_in[8];
    float* out = (float*)d_out;

    float* ws    = (float*)d_ws;
    float* wDyn  = ws;                        // 16*1152 = 18432 floats
    float* biasA = ws + 18432;                // 16*16   = 256 floats

    k_hdyn<<<dim3(9, BN), 128, 0, stream>>>(fi, W1, b1, Wd, bd, Wb, bb, dfn,
                                            wDyn, biasA);
    k_conv<<<dim3(2, 112, BN), 128, 0, stream>>>(inpt, wDyn, biasA, out);
}

// Round 23
// 45.653 us; speedup vs baseline: 1.0403x; 1.0403x over previous
//
#include <hip/hip_runtime.h>
#include <math.h>

// Problem constants
constexpr int BN  = 16;    // batch
constexpr int HH  = 224;
constexpr int WW  = 224;
constexpr int CI  = 8;     // input channels
constexpr int FF  = 256;   // filter feature dim
constexpr int NC  = 16;    // output channels
constexpr int NP  = 1152;  // CI*NC*3*3 dynamic params per sample
// reference patch index p = cin*9 + dy*3 + dx ; w[b][p][c] = dyn[b][p*16+c]
// MFMA K-ordering: k = tap*8 + cin, tap = dy*3+dx (taps 9..11 pad=0)
//
// Deterministic no-atomic pipeline, with the measured costs of r21/r22
// removed: k_h (r16 split body, 1.7 us), k_dyn = 144 independent blocks
// writing FINAL dyn columns (full K=256 per thread, bd folded, ONE plain
// store), k_conv = r17 body verbatim (~14.3 us ~ 1.15x memory floor).
// No atomics, no cross-kernel init, no B-setup fold: every workspace/output
// element is written by exactly one thread every call.

typedef __attribute__((ext_vector_type(8))) short short8;   // 8 bf16 = 4 VGPR
typedef __attribute__((ext_vector_type(4))) float f32x4;

__device__ __forceinline__ float elu_f(float x) {
    return x > 0.0f ? x : (__expf(x) - 1.0f);
}

// split f32 -> bf16 hi (truncate) + bf16 lo (residual, truncate): v ~= hi+lo
__device__ __forceinline__ void split8(const float* v, short8& hi, short8& lo) {
#pragma unroll
    for (int j = 0; j < 8; ++j) {
        const unsigned u = __float_as_uint(v[j]);
        hi[j] = (short)(u >> 16);
        const float hf = __uint_as_float(u & 0xffff0000u);
        lo[j] = (short)(__float_as_uint(v[j] - hf) >> 16);
    }
}

// -------- kernel 1: h partials, k-split x4 (hp[ks][b][col], pre-elu) ---------
// [r16-proven body, ~1.7 us measured] grid 128 blocks = (b, half, ks).
__global__ __launch_bounds__(128) void k_h(const float* __restrict__ fi,
                                           const float* __restrict__ W1,
                                           const float* __restrict__ b1,
                                           float* __restrict__ hp) {
    __shared__ float x[64];
    const int bid  = blockIdx.x;
    const int b    = bid >> 3;
    const int half = (bid >> 2) & 1;
    const int ks   = bid & 3;
    const int t    = threadIdx.x;

    if (t < 64) x[t] = fi[b * FF + ks * 64 + t];
    __syncthreads();

    const int col = half * 128 + t;
    float acc = (ks == 0) ? b1[col] : 0.0f;
#pragma unroll 8
    for (int k = 0; k < 64; ++k)
        acc = fmaf(x[k], W1[(ks * 64 + k) * FF + col], acc);
    hp[(ks * BN + b) * FF + col] = acc;
}

// ------ kernel 2: FINAL dyn columns + bias (no atomics, no k-split) ---------
// grid (9, 16) = 144 blocks, 128 threads. Block stages hs[256] =
// elu(sum of 4 hp partials) for its sample; thread t computes final column
// cg*128+t over full K=256 (two independent 128-k chains, coalesced Wd
// reads), folds bd, one plain store. cg==0 blocks also emit the bias
// (bb+dfn folded). Deterministic: one writer per element.
__global__ __launch_bounds__(128) void k_dyn(const float* __restrict__ hp,
                                             const float* __restrict__ Wd,
                                             const float* __restrict__ Wb,
                                             const float* __restrict__ bd,
                                             const float* __restrict__ bb,
                                             const float* __restrict__ dfn,
                                             float* __restrict__ w_all,
                                             float* __restrict__ bias_all) {
    __shared__ float hs[FF];
    const int cg = blockIdx.x;               // 0..8 (column group)
    const int b  = blockIdx.y;               // 0..15 (sample)
    const int t  = threadIdx.x;              // 0..127

#pragma unroll
    for (int j = 0; j < 2; ++j) {
        const int col = t + j * 128;
        const int o = b * FF + col;
        const float s = hp[o] + hp[BN * FF + o] +
                        hp[2 * BN * FF + o] + hp[3 * BN * FF + o];
        hs[col] = elu_f(s);
    }
    __syncthreads();

    const int i = cg * 128 + t;              // output column < 1152
    float a0 = bd[i], a1 = 0.0f;
#pragma unroll 8
    for (int k = 0; k < 128; ++k) {
        a0 = fmaf(hs[k],       Wd[(size_t)k * NP + i],         a0);
        a1 = fmaf(hs[k + 128], Wd[(size_t)(k + 128) * NP + i], a1);
    }
    w_all[b * NP + i] = a0 + a1;

    if (cg == 0 && t < NC) {                 // bias rides along here
        float s0 = bb[t] + dfn[t], s1 = 0.0f;
#pragma unroll 8
        for (int k = 0; k < 128; ++k) {
            s0 = fmaf(hs[k],       Wb[k * NC + t],         s0);
            s1 = fmaf(hs[k + 128], Wb[(k + 128) * NC + t], s1);
        }
        bias_all[b * NC + t] = s0 + s1;
    }
}

// ---------------- kernel 3: dynamic conv as per-sample MFMA GEMM -------------
// [r17 body verbatim, measured ~14.3 us ~ 1.15x memory floor]
__global__ __launch_bounds__(128) void k_conv(const float* __restrict__ in,
                                              const float* __restrict__ w_all,
                                              const float* __restrict__ bias_all,
                                              float* __restrict__ out) {
    __shared__ short8 lsA[4][116][2];        // [row][px][hi/lo] = 14,848 B

    const int b    = blockIdx.z;
    const int half = blockIdx.x;             // 0/1: x-half of the rows
    const int t    = threadIdx.x;
    const int wid  = t >> 6;
    const int lane = t & 63;
    const int cl   = lane & 15;
    const int g    = lane >> 4;              // k-group 0..3
    const int yb0  = blockIdx.y * 2;
    const int xb0  = half * 112;

    // ---- stage 4 rows x 114 px (hi/lo pre-split, zero-filled halo) ----
    for (int s = t; s < 456; s += 128) {
        const int r  = s / 114;
        const int j  = s - r * 114;
        const int gy = yb0 - 1 + r;
        const int gx = xb0 - 1 + j;
        const bool ok = ((unsigned)gy < (unsigned)HH) &&
                        ((unsigned)gx < (unsigned)WW);
        float av[8] = {0.f, 0.f, 0.f, 0.f, 0.f, 0.f, 0.f, 0.f};
        if (ok) {
            const float4* pp =
                (const float4*)(in + ((size_t)(b * HH + gy) * WW + gx) * CI);
            const float4 a0 = pp[0];
            const float4 a1 = pp[1];
            av[0] = a0.x; av[1] = a0.y; av[2] = a0.z; av[3] = a0.w;
            av[4] = a1.x; av[5] = a1.y; av[6] = a1.z; av[7] = a1.w;
        }
        short8 hi, lo;
        split8(av, hi, lo);
        lsA[r][j][0] = hi;
        lsA[r][j][1] = lo;
    }

    // ---- per-lane tap geometry for the 3 k-chunks ----
    int  dyL[3], dxL[3];
    bool real[3];
#pragma unroll
    for (int c = 0; c < 3; ++c) {
        const int tap = c * 4 + g;
        real[c] = (tap < 9);
        const int tp = real[c] ? tap : 0;
        dyL[c] = tp / 3;
        dxL[c] = tp - 3 * dyL[c];
    }

    // ---- weight fragments (hi/lo), loaded once per wave ----
    const float* __restrict__ wq = w_all + b * NP;
    short8 bhi0, blo0, bhi1, blo1, bhi2, blo2;
    {
        float wv[8];
#pragma unroll
        for (int i = 0; i < 8; ++i)
            wv[i] = real[0] ? wq[(i * 9 + (0 * 4 + g)) * NC + cl] : 0.0f;
        split8(wv, bhi0, blo0);
#pragma unroll
        for (int i = 0; i < 8; ++i)
            wv[i] = real[1] ? wq[(i * 9 + (1 * 4 + g)) * NC + cl] : 0.0f;
        split8(wv, bhi1, blo1);
#pragma unroll
        for (int i = 0; i < 8; ++i)
            wv[i] = real[2] ? wq[(i * 9 + (2 * 4 + g)) * NC + cl] : 0.0f;
        split8(wv, bhi2, blo2);
    }

    __syncthreads();

    const float4 bias4 = ((const float4*)(bias_all + b * NC))[g];
    const int y = yb0 + wid;
    const size_t orow = ((size_t)(b * HH + y) * WW) * NC;

#pragma unroll 1
    for (int tx = 0; tx < 7; ++tx) {
        const int x0 = xb0 + tx * 16;
        f32x4 accM = {bias4.x, bias4.y, bias4.z, bias4.w};   // hi*hi
        f32x4 accL = {0.f, 0.f, 0.f, 0.f};                   // hiW*loA
        f32x4 accH = {0.f, 0.f, 0.f, 0.f};                   // loW*hiA

#pragma unroll
        for (int c = 0; c < 3; ++c) {
            const int j = tx * 16 + cl + dxL[c];             // 0..113
            const int r = wid + dyL[c];                      // 0..3
            const short8 ahi = lsA[r][j][0];
            const short8 alo = lsA[r][j][1];
            const short8 bh = (c == 0) ? bhi0 : (c == 1) ? bhi1 : bhi2;
            const short8 bl = (c == 0) ? blo0 : (c == 1) ? blo1 : blo2;
            accM = __builtin_amdgcn_mfma_f32_16x16x32_bf16(bh, ahi, accM, 0, 0, 0);
            accL = __builtin_amdgcn_mfma_f32_16x16x32_bf16(bh, alo, accL, 0, 0, 0);
            accH = __builtin_amdgcn_mfma_f32_16x16x32_bf16(bl, ahi, accH, 0, 0, 0);
        }

        // ---- epilogue: elu + ONE float4 store (4 channels of pixel x0+cl) --
        float4 res;
        res.x = elu_f(accM[0] + accL[0] + accH[0]);
        res.y = elu_f(accM[1] + accL[1] + accH[1]);
        res.z = elu_f(accM[2] + accL[2] + accH[2]);
        res.w = elu_f(accM[3] + accL[3] + accH[3]);
        ((float4*)(out + orow + (size_t)(x0 + cl) * NC))[g] = res;
    }
}

extern "C" void kernel_launch(void* const* d_in, const int* in_sizes, int n_in,
                              void* d_out, int out_size, void* d_ws, size_t ws_size,
                              hipStream_t stream) {
    const float* inpt = (const float*)d_in[0];
    const float* fi   = (const float*)d_in[1];
    const float* W1   = (const float*)d_in[2];
    const float* b1   = (const float*)d_in[3];
    const float* Wd   = (const float*)d_in[4];
    const float* bd   = (const float*)d_in[5];
    const float* Wb   = (const float*)d_in[6];
    const float* bb   = (const float*)d_in[7];
    const float* dfn  = (const float*)d_in[8];
    float* out = (float*)d_out;

    float* ws    = (float*)d_ws;
    float* hp    = ws;                        // 4*16*256 = 16384 floats
    float* wDyn  = ws + 16384;                // 16*1152  = 18432 floats
    float* biasA = ws + 16384 + 18432;        // 16*16    = 256 floats

    k_h  <<<128, 128, 0, stream>>>(fi, W1, b1, hp);
    k_dyn<<<dim3(9, BN), 128, 0, stream>>>(hp, Wd, Wb, bd, bb, dfn,
                                           wDyn, biasA);
    k_conv<<<dim3(2, 112, BN), 128, 0, stream>>>(inpt, wDyn, biasA, out);
}